// Round 13
// baseline (175.423 us; speedup 1.0000x reference)
//
#include <hip/hip_runtime.h>
#include <math.h>

typedef __bf16 bf16x8 __attribute__((ext_vector_type(8)));
typedef __bf16 bf16x4 __attribute__((ext_vector_type(4)));
typedef float f32x4 __attribute__((ext_vector_type(4)));
typedef float f32x2 __attribute__((ext_vector_type(2)));

#define PI_D 3.14159265358979323846
// f32 two-term split of 1/(2*pi)
#define IH 0.15915494f
#define IL 6.4206383e-9f

// Barrier waiting only on LDS (lgkmcnt) — outstanding global stores keep
// retiring in the background instead of draining at every phase boundary.
__device__ __forceinline__ void bar_lds() {
  __builtin_amdgcn_sched_barrier(0);
  asm volatile("s_waitcnt lgkmcnt(0)" ::: "memory");
  __builtin_amdgcn_s_barrier();
  __builtin_amdgcn_sched_barrier(0);
}

// ---------------------------------------------------------------------------
// Setup kernel (64 blocks): pack weights into MFMA A-fragment order + tables.
// ---------------------------------------------------------------------------
__global__ void setup_kernel(const float* __restrict__ dir_W,
                             const float* __restrict__ proj1_W,
                             const float* __restrict__ proj2_W,
                             const float* __restrict__ gbf_stds,
                             const float* __restrict__ gbf_means,
                             __bf16* __restrict__ dirP, __bf16* __restrict__ p1P,
                             __bf16* __restrict__ p2P,
                             float* __restrict__ f_az, float* __restrict__ f_po,
                             f32x2* __restrict__ gAB, float* __restrict__ gcoef) {
  const int bid = blockIdx.x;
  const int tid = threadIdx.x + bid * 256;
  const int nth = 64 * 256;
  for (int o8 = tid; o8 < 8192; o8 += nth) {
    int l = o8 & 63, ks = (o8 >> 6) & 7, nt = o8 >> 9;
    int d = nt * 16 + (l & 15);
    int s0 = ks * 32 + (l >> 4) * 8;
    bf16x8 v;
#pragma unroll
    for (int j = 0; j < 8; ++j) v[j] = (__bf16)dir_W[(s0 + j) * 256 + d];
    *(bf16x8*)(dirP + o8 * 8) = v;
  }
  for (int o8 = tid; o8 < 2048; o8 += nth) {
    int l = o8 & 63, ks = (o8 >> 6) & 3, nt = o8 >> 8;
    int ko = nt * 16 + (l & 15);
    int k0 = ks * 32 + (l >> 4) * 8;
    bf16x8 v;
#pragma unroll
    for (int j = 0; j < 8; ++j) v[j] = (__bf16)proj1_W[(k0 + j) * 128 + ko];
    *(bf16x8*)(p1P + o8 * 8) = v;
  }
  for (int o8 = tid; o8 < 4096; o8 += nth) {
    int l = o8 & 63, ks = (o8 >> 6) & 3, nt = o8 >> 8;
    int d = nt * 16 + (l & 15);
    int k0 = ks * 32 + (l >> 4) * 8;
    bf16x8 v;
#pragma unroll
    for (int j = 0; j < 8; ++j) v[j] = (__bf16)proj2_W[(k0 + j) * 256 + d];
    *(bf16x8*)(p2P + o8 * 8) = v;
  }
  if (bid == 0 && threadIdx.x < 64) {
    int q = threadIdx.x;
    double l0 = log(2.0 * 1e-4);
    double l1a = log(2.0 * 2.0 * PI_D);
    double l1p = log(2.0 * PI_D);
    double ta = l0 + (l1a - l0) * (double)q / 63.0;
    double tp = l0 + (l1p - l0) * (double)q / 63.0;
    f_az[q] = (float)(2.0 * PI_D / exp(ta));
    f_po[q] = (float)(2.0 * PI_D / exp(tp));
  }
  if (bid == 1 && threadIdx.x < 128) {
    int k = threadIdx.x;
    double sd = (double)(fabsf(gbf_stds[k]) + 0.01f);
    double c = sqrt(0.7213475204444817);  // sqrt(0.5*log2(e))
    double A = c / sd;
    f32x2 ab;
    ab.x = (float)A;
    ab.y = (float)(-A * (double)gbf_means[k]);
    gAB[k] = ab;
    gcoef[k] = (float)(1.0 / (sqrt(2.0 * 3.14159) * sd));
  }
}

// ---------------------------------------------------------------------------
// Main kernel, three block types in one launch:
//   bid < 8192, even  -> dir path  (tile = bid>>1)
//   bid < 8192, odd   -> gbf path  (tile = bid>>1)
//   bid >= 8192       -> node features (tail-filler)
// Final GEMM of each path is mtl-outer: each 64-col output stripe's stores
// issue immediately after its accumulation, interleaving stores with MFMA.
// ---------------------------------------------------------------------------
__global__ __launch_bounds__(256, 4) void pair_kernel(
    const float* __restrict__ positions, const int* __restrict__ atomic_numbers,
    const float* __restrict__ gbf_mul, const float* __restrict__ gbf_bias,
    const float* __restrict__ proj1_b, const float* __restrict__ proj2_b,
    const float* __restrict__ dir_b, const __bf16* __restrict__ dirP,
    const __bf16* __restrict__ p1P, const __bf16* __restrict__ p2P,
    const float* __restrict__ f_az, const float* __restrict__ f_po,
    const f32x2* __restrict__ gAB, const float* __restrict__ gcoef,
    const float* __restrict__ emb_z, const float* __restrict__ ec,
    const float* __restrict__ cW, const float* __restrict__ cb,
    const float* __restrict__ mult_W, const float* __restrict__ charge_W,
    float* __restrict__ out_node, float* __restrict__ out_gbf,
    float* __restrict__ out_dir) {
  __shared__ __align__(16) __bf16 buf[64 * 136];
  __shared__ float s_a[64], s_b[64];  // dir: az,po ; gbf: gx,(unused)

  const int tid = threadIdx.x;
  const int bid = blockIdx.x;

  if (bid >= 8192) {
    // ========================= NODE FEATURES =========================
    int bi = bid - 8192;  // b*256 + i
    int b = bi >> 8, i = bi & 255;
    int d = tid;
    int z = (i == 0) ? 101 : atomic_numbers[b * 255 + i - 1];
    float elec = 0.0f;
    if (i != 0) {
      for (int f = 0; f < 20; ++f) elec += ec[z * 20 + f] * cW[f * 256 + d];
      elec += cb[d];
    }
    float v = emb_z[z * 256 + d] + elec + mult_W[256 + d] + charge_W[d];
    __builtin_nontemporal_store(v, &out_node[(size_t)bi * 256 + d]);
    return;
  }

  const int type = bid & 1;
  const int tile = bid >> 1;
  const int jt = tile & 3;
  const int i = (tile >> 2) & 255;
  const int b = tile >> 10;
  const int j0 = jt * 64;
  const long pairbase = ((long)(b * 256 + i)) * 256 + j0;

  const int lane = tid & 63, wv = tid >> 6;
  const int lr = lane & 15, kb = lane >> 4;

  if (type == 0) {
    // ============================ DIR PATH ============================
    const int q8 = (tid & 7) * 8;  // sinusoid freq group
    const int pr2 = tid >> 3;      // 0..31

    if (tid < 64) {
      int p = tid, j = j0 + p;
      float pxi = 0.f, pyi = 0.f, pzi = 0.f, pxj = 0.f, pyj = 0.f, pzj = 0.f;
      if (i != 0) { const float* q = positions + ((size_t)b * 255 + (i - 1)) * 3; pxi = q[0]; pyi = q[1]; pzi = q[2]; }
      if (j != 0) { const float* q = positions + ((size_t)b * 255 + (j - 1)) * 3; pxj = q[0]; pyj = q[1]; pzj = q[2]; }
      float dx = pxj - pxi, dy = pyj - pyi, dz = pzj - pzi;
      float sq = dx * dx + dy * dy + dz * dz;
      float dist = sqrtf(sq + 1e-12f);
      float inv = 1.0f / (dist + 1e-5f);
      float ndx = dx * inv, ndy = dy * inv, ndz = dz * inv;
      bool diag = (i == j);
      float xs = diag ? 1.0f : ndx;
      float ys = diag ? 0.0f : ndy;
      s_a[p] = atan2f(ys, xs);
      float cz = fminf(fmaxf(ndz, -1.0f + 1e-6f), 1.0f - 1e-6f);
      s_b[p] = acosf(cz);
    }
    bar_lds();

    f32x4 acc[4][4];
#pragma unroll
    for (int mtl = 0; mtl < 4; ++mtl)
#pragma unroll
      for (int np = 0; np < 4; ++np) acc[mtl][np] = (f32x4){0.f, 0.f, 0.f, 0.f};

    // ---- half 0 (azimuth, k 0..127): stage + ksl-outer MFMA ----
    {
      float fv[8];
#pragma unroll
      for (int t = 0; t < 8; ++t) fv[t] = f_az[q8 + t];
#pragma unroll
      for (int it = 0; it < 2; ++it) {
        int p = pr2 + it * 32;
        float ang = s_a[p];
        bf16x8 sv, cv;
#pragma unroll
        for (int t = 0; t < 8; ++t) {
          float ph = ang * fv[t];                     // f32 product, as reference
          float n = __builtin_rintf(ph * IH);
          float fr = __builtin_fmaf(ph, IH, -n) + ph * IL;
          sv[t] = (__bf16)__builtin_amdgcn_sinf(fr);  // sin(2*pi*x)
          cv[t] = (__bf16)__builtin_amdgcn_cosf(fr);
        }
        *(bf16x8*)(buf + p * 136 + q8) = sv;
        *(bf16x8*)(buf + p * 136 + 64 + q8) = cv;
      }
      bar_lds();
#pragma unroll
      for (int ksl = 0; ksl < 4; ++ksl) {
        bf16x8 bfr[4];
#pragma unroll
        for (int np = 0; np < 4; ++np)
          bfr[np] = *(const bf16x8*)(buf + (np * 16 + lr) * 136 + ksl * 32 + kb * 8);
#pragma unroll
        for (int mtl = 0; mtl < 4; ++mtl) {
          int mtile = mtl * 4 + wv;
          bf16x8 af = *(const bf16x8*)(dirP + (((size_t)mtile * 8 + ksl) * 64 + lane) * 8);
#pragma unroll
          for (int np = 0; np < 4; ++np)
            acc[mtl][np] = __builtin_amdgcn_mfma_f32_16x16x32_bf16(af, bfr[np], acc[mtl][np], 0, 0, 0);
        }
      }
      bar_lds();  // buf fully consumed; safe to restage
    }

    // ---- half 1 (polar, k 128..255): stage + mtl-outer MFMA + stores ----
    {
      float fv[8];
#pragma unroll
      for (int t = 0; t < 8; ++t) fv[t] = f_po[q8 + t];
#pragma unroll
      for (int it = 0; it < 2; ++it) {
        int p = pr2 + it * 32;
        float ang = s_b[p];
        bf16x8 sv, cv;
#pragma unroll
        for (int t = 0; t < 8; ++t) {
          float ph = ang * fv[t];
          float n = __builtin_rintf(ph * IH);
          float fr = __builtin_fmaf(ph, IH, -n) + ph * IL;
          sv[t] = (__bf16)__builtin_amdgcn_sinf(fr);
          cv[t] = (__bf16)__builtin_amdgcn_cosf(fr);
        }
        *(bf16x8*)(buf + p * 136 + q8) = sv;
        *(bf16x8*)(buf + p * 136 + 64 + q8) = cv;
      }
      bar_lds();
#pragma unroll
      for (int mtl = 0; mtl < 4; ++mtl) {
        int mtile = mtl * 4 + wv;
#pragma unroll
        for (int ksl = 0; ksl < 4; ++ksl) {
          bf16x8 bfr[4];
#pragma unroll
          for (int np = 0; np < 4; ++np)
            bfr[np] = *(const bf16x8*)(buf + (np * 16 + lr) * 136 + ksl * 32 + kb * 8);
          bf16x8 af = *(const bf16x8*)(dirP + (((size_t)mtile * 8 + 4 + ksl) * 64 + lane) * 8);
#pragma unroll
          for (int np = 0; np < 4; ++np)
            acc[mtl][np] = __builtin_amdgcn_mfma_f32_16x16x32_bf16(af, bfr[np], acc[mtl][np], 0, 0, 0);
        }
        // stripe complete -> store now, interleaved with next stripe's MFMA
        int dcol0 = mtile * 16 + kb * 4;
        f32x4 bias = *(const f32x4*)(dir_b + dcol0);
#pragma unroll
        for (int np = 0; np < 4; ++np) {
          f32x4 v = acc[mtl][np] + bias;
          __builtin_nontemporal_store(v, (f32x4*)(out_dir + (pairbase + np * 16 + lr) * 256 + dcol0));
        }
        __builtin_amdgcn_sched_barrier(0);  // pin store issue before next stripe
      }
    }
    return;
  }

  // ============================ GBF PATH ============================
  const int k0g = (tid & 15) * 8;  // gauss k group
  const int prow = tid >> 4;       // 0..15

  // preload gauss tables (before any stores are outstanding)
  f32x2 abv[8];
  float gcv[8];
#pragma unroll
  for (int t = 0; t < 8; ++t) { abv[t] = gAB[k0g + t]; gcv[t] = gcoef[k0g + t]; }

  if (tid < 64) {
    int p = tid, j = j0 + p;
    float pxi = 0.f, pyi = 0.f, pzi = 0.f, pxj = 0.f, pyj = 0.f, pzj = 0.f;
    if (i != 0) { const float* q = positions + ((size_t)b * 255 + (i - 1)) * 3; pxi = q[0]; pyi = q[1]; pzi = q[2]; }
    if (j != 0) { const float* q = positions + ((size_t)b * 255 + (j - 1)) * 3; pxj = q[0]; pyj = q[1]; pzj = q[2]; }
    float dx = pxj - pxi, dy = pyj - pyi, dz = pzj - pzi;
    float sq = dx * dx + dy * dy + dz * dz;
    float dist = sqrtf(sq + 1e-12f);
    int zi = (i == 0) ? 101 : atomic_numbers[b * 255 + i - 1];
    int zj = ((j == 0) ? 101 : atomic_numbers[b * 255 + j - 1]) + 128;
    float mul = gbf_mul[zi] + gbf_mul[zj];
    float bia = gbf_bias[zi] + gbf_bias[zj];
    s_a[p] = mul * dist + bia;
  }
  bar_lds();

#pragma unroll
  for (int it = 0; it < 4; ++it) {
    int p = prow + it * 16;
    float gx = s_a[p];
    bf16x8 gv;
#pragma unroll
    for (int t = 0; t < 8; ++t) {
      float y = __builtin_fmaf(gx, abv[t].x, abv[t].y);
      gv[t] = (__bf16)(exp2f(-y * y) * gcv[t]);
    }
    *(bf16x8*)(buf + p * 136 + k0g) = gv;
  }
  bar_lds();

  // ---- proj1 ----
  f32x4 acc1[2][4];
#pragma unroll
  for (int mtl = 0; mtl < 2; ++mtl)
#pragma unroll
    for (int np = 0; np < 4; ++np) acc1[mtl][np] = (f32x4){0.f, 0.f, 0.f, 0.f};
#pragma unroll
  for (int ksl = 0; ksl < 4; ++ksl) {
    bf16x8 bfr[4];
#pragma unroll
    for (int np = 0; np < 4; ++np)
      bfr[np] = *(const bf16x8*)(buf + (np * 16 + lr) * 136 + ksl * 32 + kb * 8);
#pragma unroll
    for (int mtl = 0; mtl < 2; ++mtl) {
      int mtile = mtl * 4 + wv;
      bf16x8 af = *(const bf16x8*)(p1P + (((size_t)mtile * 4 + ksl) * 64 + lane) * 8);
#pragma unroll
      for (int np = 0; np < 4; ++np)
        acc1[mtl][np] = __builtin_amdgcn_mfma_f32_16x16x32_bf16(af, bfr[np], acc1[mtl][np], 0, 0, 0);
    }
  }
  bar_lds();  // gauss fully consumed before h overwrites buf

  // ---- GELU -> buf ----
#pragma unroll
  for (int mtl = 0; mtl < 2; ++mtl) {
    int ko0 = (mtl * 4 + wv) * 16 + kb * 4;
    f32x4 pb = *(const f32x4*)(proj1_b + ko0);
#pragma unroll
    for (int np = 0; np < 4; ++np) {
      f32x4 hv = acc1[mtl][np] + pb;
      bf16x4 hb;
#pragma unroll
      for (int r = 0; r < 4; ++r) {
        float v = hv[r];
        v = 0.5f * v * (1.0f + erff(v * 0.70710678118654752f));
        hb[r] = (__bf16)v;
      }
      *(bf16x4*)(buf + (np * 16 + lr) * 136 + ko0) = hb;
    }
  }
  bar_lds();

  // ---- proj2: mtl-outer, stores interleaved per stripe ----
#pragma unroll
  for (int mtl = 0; mtl < 4; ++mtl) {
    int mtile = mtl * 4 + wv;
    f32x4 acc2[4];
#pragma unroll
    for (int np = 0; np < 4; ++np) acc2[np] = (f32x4){0.f, 0.f, 0.f, 0.f};
#pragma unroll
    for (int ksl = 0; ksl < 4; ++ksl) {
      bf16x8 bfr[4];
#pragma unroll
      for (int np = 0; np < 4; ++np)
        bfr[np] = *(const bf16x8*)(buf + (np * 16 + lr) * 136 + ksl * 32 + kb * 8);
      bf16x8 af = *(const bf16x8*)(p2P + (((size_t)mtile * 4 + ksl) * 64 + lane) * 8);
#pragma unroll
      for (int np = 0; np < 4; ++np)
        acc2[np] = __builtin_amdgcn_mfma_f32_16x16x32_bf16(af, bfr[np], acc2[np], 0, 0, 0);
    }
    int dcol0 = mtile * 16 + kb * 4;
    f32x4 bias = *(const f32x4*)(proj2_b + dcol0);
#pragma unroll
    for (int np = 0; np < 4; ++np) {
      f32x4 v = acc2[np] + bias;
      __builtin_nontemporal_store(v, (f32x4*)(out_gbf + (pairbase + np * 16 + lr) * 256 + dcol0));
    }
    __builtin_amdgcn_sched_barrier(0);  // pin store issue before next stripe
  }
}

extern "C" void kernel_launch(void* const* d_in, const int* in_sizes, int n_in,
                              void* d_out, int out_size, void* d_ws, size_t ws_size,
                              hipStream_t stream) {
  const float* positions = (const float*)d_in[0];
  const int* atomic_numbers = (const int*)d_in[1];
  const float* emb_z = (const float*)d_in[2];
  const float* electron_config = (const float*)d_in[3];
  const float* config_W = (const float*)d_in[4];
  const float* config_b = (const float*)d_in[5];
  const float* mult_W = (const float*)d_in[6];
  const float* charge_W = (const float*)d_in[7];
  const float* gbf_means = (const float*)d_in[8];
  const float* gbf_stds = (const float*)d_in[9];
  const float* gbf_mul = (const float*)d_in[10];
  const float* gbf_bias = (const float*)d_in[11];
  const float* proj1_W = (const float*)d_in[12];
  const float* proj1_b = (const float*)d_in[13];
  const float* proj2_W = (const float*)d_in[14];
  const float* proj2_b = (const float*)d_in[15];
  const float* dir_W = (const float*)d_in[16];
  const float* dir_b = (const float*)d_in[17];

  float* out = (float*)d_out;
  float* out_node = out;
  float* out_gbf = out + 262144;
  float* out_dir = out + 262144 + 67108864;

  char* ws = (char*)d_ws;
  __bf16* dirP = (__bf16*)(ws);
  __bf16* p1P = (__bf16*)(ws + 131072);
  __bf16* p2P = (__bf16*)(ws + 163840);
  float* f_az = (float*)(ws + 229376);
  float* f_po = (float*)(ws + 229376 + 256);
  f32x2* gAB = (f32x2*)(ws + 229376 + 512);
  float* gcoef = (float*)(ws + 229376 + 1536);

  setup_kernel<<<64, 256, 0, stream>>>(dir_W, proj1_W, proj2_W, gbf_stds, gbf_means,
                                       dirP, p1P, p2P, f_az, f_po, gAB, gcoef);
  pair_kernel<<<9216, 256, 0, stream>>>(positions, atomic_numbers, gbf_mul, gbf_bias,
                                        proj1_b, proj2_b, dir_b, dirP, p1P, p2P,
                                        f_az, f_po, gAB, gcoef,
                                        emb_z, electron_config, config_W, config_b,
                                        mult_W, charge_W,
                                        out_node, out_gbf, out_dir);
}

// Round 14
// 168.143 us; speedup vs baseline: 1.0433x; 1.0433x over previous
//
#include <hip/hip_runtime.h>
#include <math.h>

typedef __bf16 bf16x8 __attribute__((ext_vector_type(8)));
typedef __bf16 bf16x4 __attribute__((ext_vector_type(4)));
typedef float f32x4 __attribute__((ext_vector_type(4)));
typedef float f32x2 __attribute__((ext_vector_type(2)));

#define PI_D 3.14159265358979323846
// f32 two-term split of 1/(2*pi)
#define IH 0.15915494f
#define IL 6.4206383e-9f

// Barrier waiting only on LDS (lgkmcnt) — outstanding global stores keep
// retiring in the background instead of draining at every phase boundary.
__device__ __forceinline__ void bar_lds() {
  __builtin_amdgcn_sched_barrier(0);
  asm volatile("s_waitcnt lgkmcnt(0)" ::: "memory");
  __builtin_amdgcn_s_barrier();
  __builtin_amdgcn_sched_barrier(0);
}

// ---------------------------------------------------------------------------
// Setup kernel (64 blocks): pack weights into MFMA A-fragment order + tables.
// ---------------------------------------------------------------------------
__global__ void setup_kernel(const float* __restrict__ dir_W,
                             const float* __restrict__ proj1_W,
                             const float* __restrict__ proj2_W,
                             const float* __restrict__ gbf_stds,
                             const float* __restrict__ gbf_means,
                             __bf16* __restrict__ dirP, __bf16* __restrict__ p1P,
                             __bf16* __restrict__ p2P,
                             float* __restrict__ f_az, float* __restrict__ f_po,
                             f32x2* __restrict__ gAB, float* __restrict__ gcoef) {
  const int bid = blockIdx.x;
  const int tid = threadIdx.x + bid * 256;
  const int nth = 64 * 256;
  for (int o8 = tid; o8 < 8192; o8 += nth) {
    int l = o8 & 63, ks = (o8 >> 6) & 7, nt = o8 >> 9;
    int d = nt * 16 + (l & 15);
    int s0 = ks * 32 + (l >> 4) * 8;
    bf16x8 v;
#pragma unroll
    for (int j = 0; j < 8; ++j) v[j] = (__bf16)dir_W[(s0 + j) * 256 + d];
    *(bf16x8*)(dirP + o8 * 8) = v;
  }
  for (int o8 = tid; o8 < 2048; o8 += nth) {
    int l = o8 & 63, ks = (o8 >> 6) & 3, nt = o8 >> 8;
    int ko = nt * 16 + (l & 15);
    int k0 = ks * 32 + (l >> 4) * 8;
    bf16x8 v;
#pragma unroll
    for (int j = 0; j < 8; ++j) v[j] = (__bf16)proj1_W[(k0 + j) * 128 + ko];
    *(bf16x8*)(p1P + o8 * 8) = v;
  }
  for (int o8 = tid; o8 < 4096; o8 += nth) {
    int l = o8 & 63, ks = (o8 >> 6) & 3, nt = o8 >> 8;
    int d = nt * 16 + (l & 15);
    int k0 = ks * 32 + (l >> 4) * 8;
    bf16x8 v;
#pragma unroll
    for (int j = 0; j < 8; ++j) v[j] = (__bf16)proj2_W[(k0 + j) * 256 + d];
    *(bf16x8*)(p2P + o8 * 8) = v;
  }
  if (bid == 0 && threadIdx.x < 64) {
    int q = threadIdx.x;
    double l0 = log(2.0 * 1e-4);
    double l1a = log(2.0 * 2.0 * PI_D);
    double l1p = log(2.0 * PI_D);
    double ta = l0 + (l1a - l0) * (double)q / 63.0;
    double tp = l0 + (l1p - l0) * (double)q / 63.0;
    f_az[q] = (float)(2.0 * PI_D / exp(ta));
    f_po[q] = (float)(2.0 * PI_D / exp(tp));
  }
  if (bid == 1 && threadIdx.x < 128) {
    int k = threadIdx.x;
    double sd = (double)(fabsf(gbf_stds[k]) + 0.01f);
    double c = sqrt(0.7213475204444817);  // sqrt(0.5*log2(e))
    double A = c / sd;
    f32x2 ab;
    ab.x = (float)A;
    ab.y = (float)(-A * (double)gbf_means[k]);
    gAB[k] = ab;
    gcoef[k] = (float)(1.0 / (sqrt(2.0 * 3.14159) * sd));
  }
}

// ---------------------------------------------------------------------------
// Main kernel, 32-pair tiles (finer store granularity than r12's 64):
//   bid < 16384, even -> dir path  (tile = bid>>1)
//   bid < 16384, odd  -> gbf path  (tile = bid>>1)
//   bid >= 16384      -> node features (tail-filler)
// tile: jt = tile&7 (j-block of 32), i = (tile>>3)&255, b = tile>>11.
// Stores only at block end (no loads after stores -> no vmcnt FIFO trap).
// ---------------------------------------------------------------------------
__global__ __launch_bounds__(256, 4) void pair_kernel(
    const float* __restrict__ positions, const int* __restrict__ atomic_numbers,
    const float* __restrict__ gbf_mul, const float* __restrict__ gbf_bias,
    const float* __restrict__ proj1_b, const float* __restrict__ proj2_b,
    const float* __restrict__ dir_b, const __bf16* __restrict__ dirP,
    const __bf16* __restrict__ p1P, const __bf16* __restrict__ p2P,
    const float* __restrict__ f_az, const float* __restrict__ f_po,
    const f32x2* __restrict__ gAB, const float* __restrict__ gcoef,
    const float* __restrict__ emb_z, const float* __restrict__ ec,
    const float* __restrict__ cW, const float* __restrict__ cb,
    const float* __restrict__ mult_W, const float* __restrict__ charge_W,
    float* __restrict__ out_node, float* __restrict__ out_gbf,
    float* __restrict__ out_dir) {
  __shared__ __align__(16) __bf16 buf[32 * 136];
  __shared__ float s_a[32], s_b[32];  // dir: az,po ; gbf: gx,(unused)

  const int tid = threadIdx.x;
  const int bid = blockIdx.x;

  if (bid >= 16384) {
    // ========================= NODE FEATURES =========================
    int bi = bid - 16384;  // b*256 + i
    int b = bi >> 8, i = bi & 255;
    int d = tid;
    int z = (i == 0) ? 101 : atomic_numbers[b * 255 + i - 1];
    float elec = 0.0f;
    if (i != 0) {
      for (int f = 0; f < 20; ++f) elec += ec[z * 20 + f] * cW[f * 256 + d];
      elec += cb[d];
    }
    float v = emb_z[z * 256 + d] + elec + mult_W[256 + d] + charge_W[d];
    __builtin_nontemporal_store(v, &out_node[(size_t)bi * 256 + d]);
    return;
  }

  const int type = bid & 1;
  const int tile = bid >> 1;
  const int jt = tile & 7;
  const int i = (tile >> 3) & 255;
  const int b = tile >> 11;
  const int j0 = jt * 32;
  const long pairbase = ((long)(b * 256 + i)) * 256 + j0;

  const int lane = tid & 63, wv = tid >> 6;
  const int lr = lane & 15, kb = lane >> 4;

  if (type == 0) {
    // ============================ DIR PATH ============================
    const int q8 = (tid & 7) * 8;  // sinusoid freq group
    const int pr = tid >> 3;       // 0..31 (row)

    if (tid < 32) {
      int p = tid, j = j0 + p;
      float pxi = 0.f, pyi = 0.f, pzi = 0.f, pxj = 0.f, pyj = 0.f, pzj = 0.f;
      if (i != 0) { const float* q = positions + ((size_t)b * 255 + (i - 1)) * 3; pxi = q[0]; pyi = q[1]; pzi = q[2]; }
      if (j != 0) { const float* q = positions + ((size_t)b * 255 + (j - 1)) * 3; pxj = q[0]; pyj = q[1]; pzj = q[2]; }
      float dx = pxj - pxi, dy = pyj - pyi, dz = pzj - pzi;
      float sq = dx * dx + dy * dy + dz * dz;
      float dist = sqrtf(sq + 1e-12f);
      float inv = 1.0f / (dist + 1e-5f);
      float ndx = dx * inv, ndy = dy * inv, ndz = dz * inv;
      bool diag = (i == j);
      float xs = diag ? 1.0f : ndx;
      float ys = diag ? 0.0f : ndy;
      s_a[p] = atan2f(ys, xs);
      float cz = fminf(fmaxf(ndz, -1.0f + 1e-6f), 1.0f - 1e-6f);
      s_b[p] = acosf(cz);
    }
    bar_lds();

    f32x4 acc[4][2];
#pragma unroll
    for (int mtl = 0; mtl < 4; ++mtl)
#pragma unroll
      for (int np = 0; np < 2; ++np) acc[mtl][np] = (f32x4){0.f, 0.f, 0.f, 0.f};

    for (int half = 0; half < 2; ++half) {
      const float* ft = half ? f_po : f_az;
      float fv[8];
#pragma unroll
      for (int t = 0; t < 8; ++t) fv[t] = ft[q8 + t];
      {
        float ang = half ? s_b[pr] : s_a[pr];
        bf16x8 sv, cv;
#pragma unroll
        for (int t = 0; t < 8; ++t) {
          float ph = ang * fv[t];                     // f32 product, as reference
          float n = __builtin_rintf(ph * IH);
          float fr = __builtin_fmaf(ph, IH, -n) + ph * IL;
          sv[t] = (__bf16)__builtin_amdgcn_sinf(fr);  // sin(2*pi*x)
          cv[t] = (__bf16)__builtin_amdgcn_cosf(fr);
        }
        *(bf16x8*)(buf + pr * 136 + q8) = sv;
        *(bf16x8*)(buf + pr * 136 + 64 + q8) = cv;
      }
      bar_lds();
#pragma unroll
      for (int ksl = 0; ksl < 4; ++ksl) {
        int ks = half * 4 + ksl;
        bf16x8 bfr[2];
#pragma unroll
        for (int np = 0; np < 2; ++np)
          bfr[np] = *(const bf16x8*)(buf + (np * 16 + lr) * 136 + ksl * 32 + kb * 8);
#pragma unroll
        for (int mtl = 0; mtl < 4; ++mtl) {
          int mtile = mtl * 4 + wv;
          bf16x8 af = *(const bf16x8*)(dirP + (((size_t)mtile * 8 + ks) * 64 + lane) * 8);
#pragma unroll
          for (int np = 0; np < 2; ++np)
            acc[mtl][np] = __builtin_amdgcn_mfma_f32_16x16x32_bf16(af, bfr[np], acc[mtl][np], 0, 0, 0);
        }
      }
      bar_lds();
    }

#pragma unroll
    for (int mtl = 0; mtl < 4; ++mtl) {
      int dcol0 = (mtl * 4 + wv) * 16 + kb * 4;
      f32x4 bias = *(const f32x4*)(dir_b + dcol0);
#pragma unroll
      for (int np = 0; np < 2; ++np) {
        f32x4 v = acc[mtl][np] + bias;
        __builtin_nontemporal_store(v, (f32x4*)(out_dir + (pairbase + np * 16 + lr) * 256 + dcol0));
      }
    }
    return;
  }

  // ============================ GBF PATH ============================
  const int k0g = (tid & 15) * 8;  // gauss k group
  const int prow = tid >> 4;       // 0..15

  // preload gauss tables (before any stores are outstanding)
  f32x2 abv[8];
  float gcv[8];
#pragma unroll
  for (int t = 0; t < 8; ++t) { abv[t] = gAB[k0g + t]; gcv[t] = gcoef[k0g + t]; }

  if (tid < 32) {
    int p = tid, j = j0 + p;
    float pxi = 0.f, pyi = 0.f, pzi = 0.f, pxj = 0.f, pyj = 0.f, pzj = 0.f;
    if (i != 0) { const float* q = positions + ((size_t)b * 255 + (i - 1)) * 3; pxi = q[0]; pyi = q[1]; pzi = q[2]; }
    if (j != 0) { const float* q = positions + ((size_t)b * 255 + (j - 1)) * 3; pxj = q[0]; pyj = q[1]; pzj = q[2]; }
    float dx = pxj - pxi, dy = pyj - pyi, dz = pzj - pzi;
    float sq = dx * dx + dy * dy + dz * dz;
    float dist = sqrtf(sq + 1e-12f);
    int zi = (i == 0) ? 101 : atomic_numbers[b * 255 + i - 1];
    int zj = ((j == 0) ? 101 : atomic_numbers[b * 255 + j - 1]) + 128;
    float mul = gbf_mul[zi] + gbf_mul[zj];
    float bia = gbf_bias[zi] + gbf_bias[zj];
    s_a[p] = mul * dist + bia;
  }
  bar_lds();

#pragma unroll
  for (int it = 0; it < 2; ++it) {
    int p = prow + it * 16;
    float gx = s_a[p];
    bf16x8 gv;
#pragma unroll
    for (int t = 0; t < 8; ++t) {
      float y = __builtin_fmaf(gx, abv[t].x, abv[t].y);
      gv[t] = (__bf16)(exp2f(-y * y) * gcv[t]);
    }
    *(bf16x8*)(buf + p * 136 + k0g) = gv;
  }
  bar_lds();

  // ---- proj1 ----
  f32x4 acc1[2][2];
#pragma unroll
  for (int mtl = 0; mtl < 2; ++mtl)
#pragma unroll
    for (int np = 0; np < 2; ++np) acc1[mtl][np] = (f32x4){0.f, 0.f, 0.f, 0.f};
#pragma unroll
  for (int ksl = 0; ksl < 4; ++ksl) {
    bf16x8 bfr[2];
#pragma unroll
    for (int np = 0; np < 2; ++np)
      bfr[np] = *(const bf16x8*)(buf + (np * 16 + lr) * 136 + ksl * 32 + kb * 8);
#pragma unroll
    for (int mtl = 0; mtl < 2; ++mtl) {
      int mtile = mtl * 4 + wv;
      bf16x8 af = *(const bf16x8*)(p1P + (((size_t)mtile * 4 + ksl) * 64 + lane) * 8);
#pragma unroll
      for (int np = 0; np < 2; ++np)
        acc1[mtl][np] = __builtin_amdgcn_mfma_f32_16x16x32_bf16(af, bfr[np], acc1[mtl][np], 0, 0, 0);
    }
  }
  bar_lds();  // gauss fully consumed before h overwrites buf

  // ---- GELU -> buf ----
#pragma unroll
  for (int mtl = 0; mtl < 2; ++mtl) {
    int ko0 = (mtl * 4 + wv) * 16 + kb * 4;
    f32x4 pb = *(const f32x4*)(proj1_b + ko0);
#pragma unroll
    for (int np = 0; np < 2; ++np) {
      f32x4 hv = acc1[mtl][np] + pb;
      bf16x4 hb;
#pragma unroll
      for (int r = 0; r < 4; ++r) {
        float v = hv[r];
        v = 0.5f * v * (1.0f + erff(v * 0.70710678118654752f));
        hb[r] = (__bf16)v;
      }
      *(bf16x4*)(buf + (np * 16 + lr) * 136 + ko0) = hb;
    }
  }
  bar_lds();

  // ---- proj2 ----
  f32x4 acc2[4][2];
#pragma unroll
  for (int mtl = 0; mtl < 4; ++mtl)
#pragma unroll
    for (int np = 0; np < 2; ++np) acc2[mtl][np] = (f32x4){0.f, 0.f, 0.f, 0.f};
#pragma unroll
  for (int ksl = 0; ksl < 4; ++ksl) {
    bf16x8 bfr[2];
#pragma unroll
    for (int np = 0; np < 2; ++np)
      bfr[np] = *(const bf16x8*)(buf + (np * 16 + lr) * 136 + ksl * 32 + kb * 8);
#pragma unroll
    for (int mtl = 0; mtl < 4; ++mtl) {
      int mtile = mtl * 4 + wv;
      bf16x8 af = *(const bf16x8*)(p2P + (((size_t)mtile * 4 + ksl) * 64 + lane) * 8);
#pragma unroll
      for (int np = 0; np < 2; ++np)
        acc2[mtl][np] = __builtin_amdgcn_mfma_f32_16x16x32_bf16(af, bfr[np], acc2[mtl][np], 0, 0, 0);
    }
  }
#pragma unroll
  for (int mtl = 0; mtl < 4; ++mtl) {
    int dcol0 = (mtl * 4 + wv) * 16 + kb * 4;
    f32x4 bias = *(const f32x4*)(proj2_b + dcol0);
#pragma unroll
    for (int np = 0; np < 2; ++np) {
      f32x4 v = acc2[mtl][np] + bias;
      __builtin_nontemporal_store(v, (f32x4*)(out_gbf + (pairbase + np * 16 + lr) * 256 + dcol0));
    }
  }
}

extern "C" void kernel_launch(void* const* d_in, const int* in_sizes, int n_in,
                              void* d_out, int out_size, void* d_ws, size_t ws_size,
                              hipStream_t stream) {
  const float* positions = (const float*)d_in[0];
  const int* atomic_numbers = (const int*)d_in[1];
  const float* emb_z = (const float*)d_in[2];
  const float* electron_config = (const float*)d_in[3];
  const float* config_W = (const float*)d_in[4];
  const float* config_b = (const float*)d_in[5];
  const float* mult_W = (const float*)d_in[6];
  const float* charge_W = (const float*)d_in[7];
  const float* gbf_means = (const float*)d_in[8];
  const float* gbf_stds = (const float*)d_in[9];
  const float* gbf_mul = (const float*)d_in[10];
  const float* gbf_bias = (const float*)d_in[11];
  const float* proj1_W = (const float*)d_in[12];
  const float* proj1_b = (const float*)d_in[13];
  const float* proj2_W = (const float*)d_in[14];
  const float* proj2_b = (const float*)d_in[15];
  const float* dir_W = (const float*)d_in[16];
  const float* dir_b = (const float*)d_in[17];

  float* out = (float*)d_out;
  float* out_node = out;
  float* out_gbf = out + 262144;
  float* out_dir = out + 262144 + 67108864;

  char* ws = (char*)d_ws;
  __bf16* dirP = (__bf16*)(ws);
  __bf16* p1P = (__bf16*)(ws + 131072);
  __bf16* p2P = (__bf16*)(ws + 163840);
  float* f_az = (float*)(ws + 229376);
  float* f_po = (float*)(ws + 229376 + 256);
  f32x2* gAB = (f32x2*)(ws + 229376 + 512);
  float* gcoef = (float*)(ws + 229376 + 1536);

  setup_kernel<<<64, 256, 0, stream>>>(dir_W, proj1_W, proj2_W, gbf_stds, gbf_means,
                                       dirP, p1P, p2P, f_az, f_po, gAB, gcoef);
  pair_kernel<<<17408, 256, 0, stream>>>(positions, atomic_numbers, gbf_mul, gbf_bias,
                                         proj1_b, proj2_b, dir_b, dirP, p1P, p2P,
                                         f_az, f_po, gAB, gcoef,
                                         emb_z, electron_config, config_W, config_b,
                                         mult_W, charge_W,
                                         out_node, out_gbf, out_dir);
}

// Round 15
// 144.867 us; speedup vs baseline: 1.2109x; 1.1607x over previous
//
#include <hip/hip_runtime.h>
#include <math.h>

typedef __bf16 bf16x8 __attribute__((ext_vector_type(8)));
typedef __bf16 bf16x4 __attribute__((ext_vector_type(4)));
typedef float f32x4 __attribute__((ext_vector_type(4)));
typedef float f32x2 __attribute__((ext_vector_type(2)));

#define PI_D 3.14159265358979323846
// f32 two-term split of 1/(2*pi)
#define IH 0.15915494f
#define IL 6.4206383e-9f

// Barrier waiting only on LDS (lgkmcnt) — outstanding global stores keep
// retiring in the background instead of draining at every phase boundary.
__device__ __forceinline__ void bar_lds() {
  __builtin_amdgcn_sched_barrier(0);
  asm volatile("s_waitcnt lgkmcnt(0)" ::: "memory");
  __builtin_amdgcn_s_barrier();
  __builtin_amdgcn_sched_barrier(0);
}

// ---------------------------------------------------------------------------
// Setup kernel (64 blocks): pack weights into MFMA A-fragment order + tables.
// ---------------------------------------------------------------------------
__global__ void setup_kernel(const float* __restrict__ dir_W,
                             const float* __restrict__ proj1_W,
                             const float* __restrict__ proj2_W,
                             const float* __restrict__ gbf_stds,
                             const float* __restrict__ gbf_means,
                             __bf16* __restrict__ dirP, __bf16* __restrict__ p1P,
                             __bf16* __restrict__ p2P,
                             float* __restrict__ f_az, float* __restrict__ f_po,
                             f32x2* __restrict__ gAB, float* __restrict__ gcoef) {
  const int bid = blockIdx.x;
  const int tid = threadIdx.x + bid * 256;
  const int nth = 64 * 256;
  for (int o8 = tid; o8 < 8192; o8 += nth) {
    int l = o8 & 63, ks = (o8 >> 6) & 7, nt = o8 >> 9;
    int d = nt * 16 + (l & 15);
    int s0 = ks * 32 + (l >> 4) * 8;
    bf16x8 v;
#pragma unroll
    for (int j = 0; j < 8; ++j) v[j] = (__bf16)dir_W[(s0 + j) * 256 + d];
    *(bf16x8*)(dirP + o8 * 8) = v;
  }
  for (int o8 = tid; o8 < 2048; o8 += nth) {
    int l = o8 & 63, ks = (o8 >> 6) & 3, nt = o8 >> 8;
    int ko = nt * 16 + (l & 15);
    int k0 = ks * 32 + (l >> 4) * 8;
    bf16x8 v;
#pragma unroll
    for (int j = 0; j < 8; ++j) v[j] = (__bf16)proj1_W[(k0 + j) * 128 + ko];
    *(bf16x8*)(p1P + o8 * 8) = v;
  }
  for (int o8 = tid; o8 < 4096; o8 += nth) {
    int l = o8 & 63, ks = (o8 >> 6) & 3, nt = o8 >> 8;
    int d = nt * 16 + (l & 15);
    int k0 = ks * 32 + (l >> 4) * 8;
    bf16x8 v;
#pragma unroll
    for (int j = 0; j < 8; ++j) v[j] = (__bf16)proj2_W[(k0 + j) * 256 + d];
    *(bf16x8*)(p2P + o8 * 8) = v;
  }
  if (bid == 0 && threadIdx.x < 64) {
    int q = threadIdx.x;
    double l0 = log(2.0 * 1e-4);
    double l1a = log(2.0 * 2.0 * PI_D);
    double l1p = log(2.0 * PI_D);
    double ta = l0 + (l1a - l0) * (double)q / 63.0;
    double tp = l0 + (l1p - l0) * (double)q / 63.0;
    f_az[q] = (float)(2.0 * PI_D / exp(ta));
    f_po[q] = (float)(2.0 * PI_D / exp(tp));
  }
  if (bid == 1 && threadIdx.x < 128) {
    int k = threadIdx.x;
    double sd = (double)(fabsf(gbf_stds[k]) + 0.01f);
    double c = sqrt(0.7213475204444817);  // sqrt(0.5*log2(e))
    double A = c / sd;
    f32x2 ab;
    ab.x = (float)A;
    ab.y = (float)(-A * (double)gbf_means[k]);
    gAB[k] = ab;
    gcoef[k] = (float)(1.0 / (sqrt(2.0 * 3.14159) * sd));
  }
}

// ---------------------------------------------------------------------------
// Main kernel, three block types in one launch:
//   bid < 8192, even  -> dir path  (tile = bid>>1)
//   bid < 8192, odd   -> gbf path  (tile = bid>>1)
//   bid >= 8192       -> node features (tail-filler, independent)
// The dir/gbf interleave keeps every CU on a mixed diet so HBM writes are
// fed continuously (the r11 desync win); node blocks dispatch last and fill
// the grid tail.
// ---------------------------------------------------------------------------
__global__ __launch_bounds__(256, 4) void pair_kernel(
    const float* __restrict__ positions, const int* __restrict__ atomic_numbers,
    const float* __restrict__ gbf_mul, const float* __restrict__ gbf_bias,
    const float* __restrict__ proj1_b, const float* __restrict__ proj2_b,
    const float* __restrict__ dir_b, const __bf16* __restrict__ dirP,
    const __bf16* __restrict__ p1P, const __bf16* __restrict__ p2P,
    const float* __restrict__ f_az, const float* __restrict__ f_po,
    const f32x2* __restrict__ gAB, const float* __restrict__ gcoef,
    const float* __restrict__ emb_z, const float* __restrict__ ec,
    const float* __restrict__ cW, const float* __restrict__ cb,
    const float* __restrict__ mult_W, const float* __restrict__ charge_W,
    float* __restrict__ out_node, float* __restrict__ out_gbf,
    float* __restrict__ out_dir) {
  __shared__ __align__(16) __bf16 buf[64 * 136];
  __shared__ float s_a[64], s_b[64];  // dir: az,po ; gbf: gx,(unused)

  const int tid = threadIdx.x;
  const int bid = blockIdx.x;

  if (bid >= 8192) {
    // ========================= NODE FEATURES =========================
    int bi = bid - 8192;  // b*256 + i
    int b = bi >> 8, i = bi & 255;
    int d = tid;
    int z = (i == 0) ? 101 : atomic_numbers[b * 255 + i - 1];
    float elec = 0.0f;
    if (i != 0) {
      for (int f = 0; f < 20; ++f) elec += ec[z * 20 + f] * cW[f * 256 + d];
      elec += cb[d];
    }
    float v = emb_z[z * 256 + d] + elec + mult_W[256 + d] + charge_W[d];
    __builtin_nontemporal_store(v, &out_node[(size_t)bi * 256 + d]);
    return;
  }

  const int type = bid & 1;
  const int tile = bid >> 1;
  const int jt = tile & 3;
  const int i = (tile >> 2) & 255;
  const int b = tile >> 10;
  const int j0 = jt * 64;
  const long pairbase = ((long)(b * 256 + i)) * 256 + j0;

  const int lane = tid & 63, wv = tid >> 6;
  const int lr = lane & 15, kb = lane >> 4;

  if (type == 0) {
    // ============================ DIR PATH ============================
    const int q8 = (tid & 7) * 8;  // sinusoid freq group
    const int pr2 = tid >> 3;      // 0..31

    if (tid < 64) {
      int p = tid, j = j0 + p;
      float pxi = 0.f, pyi = 0.f, pzi = 0.f, pxj = 0.f, pyj = 0.f, pzj = 0.f;
      if (i != 0) { const float* q = positions + ((size_t)b * 255 + (i - 1)) * 3; pxi = q[0]; pyi = q[1]; pzi = q[2]; }
      if (j != 0) { const float* q = positions + ((size_t)b * 255 + (j - 1)) * 3; pxj = q[0]; pyj = q[1]; pzj = q[2]; }
      float dx = pxj - pxi, dy = pyj - pyi, dz = pzj - pzi;
      float sq = dx * dx + dy * dy + dz * dz;
      float dist = sqrtf(sq + 1e-12f);
      float inv = 1.0f / (dist + 1e-5f);
      float ndx = dx * inv, ndy = dy * inv, ndz = dz * inv;
      bool diag = (i == j);
      float xs = diag ? 1.0f : ndx;
      float ys = diag ? 0.0f : ndy;
      s_a[p] = atan2f(ys, xs);
      float cz = fminf(fmaxf(ndz, -1.0f + 1e-6f), 1.0f - 1e-6f);
      s_b[p] = acosf(cz);
    }
    bar_lds();

    f32x4 acc[4][4];
#pragma unroll
    for (int mtl = 0; mtl < 4; ++mtl)
#pragma unroll
      for (int np = 0; np < 4; ++np) acc[mtl][np] = (f32x4){0.f, 0.f, 0.f, 0.f};

    for (int half = 0; half < 2; ++half) {
      const float* ft = half ? f_po : f_az;
      float fv[8];
#pragma unroll
      for (int t = 0; t < 8; ++t) fv[t] = ft[q8 + t];
#pragma unroll
      for (int it = 0; it < 2; ++it) {
        int p = pr2 + it * 32;
        float ang = half ? s_b[p] : s_a[p];
        bf16x8 sv, cv;
#pragma unroll
        for (int t = 0; t < 8; ++t) {
          float ph = ang * fv[t];                     // f32 product, as reference
          float n = __builtin_rintf(ph * IH);
          float fr = __builtin_fmaf(ph, IH, -n) + ph * IL;
          sv[t] = (__bf16)__builtin_amdgcn_sinf(fr);  // sin(2*pi*x)
          cv[t] = (__bf16)__builtin_amdgcn_cosf(fr);
        }
        *(bf16x8*)(buf + p * 136 + q8) = sv;
        *(bf16x8*)(buf + p * 136 + 64 + q8) = cv;
      }
      bar_lds();
#pragma unroll
      for (int ksl = 0; ksl < 4; ++ksl) {
        int ks = half * 4 + ksl;
        bf16x8 bfr[4];
#pragma unroll
        for (int np = 0; np < 4; ++np)
          bfr[np] = *(const bf16x8*)(buf + (np * 16 + lr) * 136 + ksl * 32 + kb * 8);
#pragma unroll
        for (int mtl = 0; mtl < 4; ++mtl) {
          int mtile = mtl * 4 + wv;
          bf16x8 af = *(const bf16x8*)(dirP + (((size_t)mtile * 8 + ks) * 64 + lane) * 8);
#pragma unroll
          for (int np = 0; np < 4; ++np)
            acc[mtl][np] = __builtin_amdgcn_mfma_f32_16x16x32_bf16(af, bfr[np], acc[mtl][np], 0, 0, 0);
        }
      }
      bar_lds();
    }

#pragma unroll
    for (int mtl = 0; mtl < 4; ++mtl) {
      int dcol0 = (mtl * 4 + wv) * 16 + kb * 4;
      f32x4 bias = *(const f32x4*)(dir_b + dcol0);
#pragma unroll
      for (int np = 0; np < 4; ++np) {
        f32x4 v = acc[mtl][np] + bias;
        __builtin_nontemporal_store(v, (f32x4*)(out_dir + (pairbase + np * 16 + lr) * 256 + dcol0));
      }
    }
    return;
  }

  // ============================ GBF PATH ============================
  const int k0g = (tid & 15) * 8;  // gauss k group
  const int prow = tid >> 4;       // 0..15

  // preload gauss tables (before any stores are outstanding)
  f32x2 abv[8];
  float gcv[8];
#pragma unroll
  for (int t = 0; t < 8; ++t) { abv[t] = gAB[k0g + t]; gcv[t] = gcoef[k0g + t]; }

  if (tid < 64) {
    int p = tid, j = j0 + p;
    float pxi = 0.f, pyi = 0.f, pzi = 0.f, pxj = 0.f, pyj = 0.f, pzj = 0.f;
    if (i != 0) { const float* q = positions + ((size_t)b * 255 + (i - 1)) * 3; pxi = q[0]; pyi = q[1]; pzi = q[2]; }
    if (j != 0) { const float* q = positions + ((size_t)b * 255 + (j - 1)) * 3; pxj = q[0]; pyj = q[1]; pzj = q[2]; }
    float dx = pxj - pxi, dy = pyj - pyi, dz = pzj - pzi;
    float sq = dx * dx + dy * dy + dz * dz;
    float dist = sqrtf(sq + 1e-12f);
    int zi = (i == 0) ? 101 : atomic_numbers[b * 255 + i - 1];
    int zj = ((j == 0) ? 101 : atomic_numbers[b * 255 + j - 1]) + 128;
    float mul = gbf_mul[zi] + gbf_mul[zj];
    float bia = gbf_bias[zi] + gbf_bias[zj];
    s_a[p] = mul * dist + bia;
  }
  bar_lds();

#pragma unroll
  for (int it = 0; it < 4; ++it) {
    int p = prow + it * 16;
    float gx = s_a[p];
    bf16x8 gv;
#pragma unroll
    for (int t = 0; t < 8; ++t) {
      float y = __builtin_fmaf(gx, abv[t].x, abv[t].y);
      gv[t] = (__bf16)(exp2f(-y * y) * gcv[t]);
    }
    *(bf16x8*)(buf + p * 136 + k0g) = gv;
  }
  bar_lds();

  // ---- proj1 ----
  f32x4 acc1[2][4];
#pragma unroll
  for (int mtl = 0; mtl < 2; ++mtl)
#pragma unroll
    for (int np = 0; np < 4; ++np) acc1[mtl][np] = (f32x4){0.f, 0.f, 0.f, 0.f};
#pragma unroll
  for (int ksl = 0; ksl < 4; ++ksl) {
    bf16x8 bfr[4];
#pragma unroll
    for (int np = 0; np < 4; ++np)
      bfr[np] = *(const bf16x8*)(buf + (np * 16 + lr) * 136 + ksl * 32 + kb * 8);
#pragma unroll
    for (int mtl = 0; mtl < 2; ++mtl) {
      int mtile = mtl * 4 + wv;
      bf16x8 af = *(const bf16x8*)(p1P + (((size_t)mtile * 4 + ksl) * 64 + lane) * 8);
#pragma unroll
      for (int np = 0; np < 4; ++np)
        acc1[mtl][np] = __builtin_amdgcn_mfma_f32_16x16x32_bf16(af, bfr[np], acc1[mtl][np], 0, 0, 0);
    }
  }
  bar_lds();  // gauss fully consumed before h overwrites buf

  // ---- GELU -> buf ----
#pragma unroll
  for (int mtl = 0; mtl < 2; ++mtl) {
    int ko0 = (mtl * 4 + wv) * 16 + kb * 4;
    f32x4 pb = *(const f32x4*)(proj1_b + ko0);
#pragma unroll
    for (int np = 0; np < 4; ++np) {
      f32x4 hv = acc1[mtl][np] + pb;
      bf16x4 hb;
#pragma unroll
      for (int r = 0; r < 4; ++r) {
        float v = hv[r];
        v = 0.5f * v * (1.0f + erff(v * 0.70710678118654752f));
        hb[r] = (__bf16)v;
      }
      *(bf16x4*)(buf + (np * 16 + lr) * 136 + ko0) = hb;
    }
  }
  bar_lds();

  // ---- proj2 ----
  f32x4 acc2[4][4];
#pragma unroll
  for (int mtl = 0; mtl < 4; ++mtl)
#pragma unroll
    for (int np = 0; np < 4; ++np) acc2[mtl][np] = (f32x4){0.f, 0.f, 0.f, 0.f};
#pragma unroll
  for (int ksl = 0; ksl < 4; ++ksl) {
    bf16x8 bfr[4];
#pragma unroll
    for (int np = 0; np < 4; ++np)
      bfr[np] = *(const bf16x8*)(buf + (np * 16 + lr) * 136 + ksl * 32 + kb * 8);
#pragma unroll
    for (int mtl = 0; mtl < 4; ++mtl) {
      int mtile = mtl * 4 + wv;
      bf16x8 af = *(const bf16x8*)(p2P + (((size_t)mtile * 4 + ksl) * 64 + lane) * 8);
#pragma unroll
      for (int np = 0; np < 4; ++np)
        acc2[mtl][np] = __builtin_amdgcn_mfma_f32_16x16x32_bf16(af, bfr[np], acc2[mtl][np], 0, 0, 0);
    }
  }
#pragma unroll
  for (int mtl = 0; mtl < 4; ++mtl) {
    int dcol0 = (mtl * 4 + wv) * 16 + kb * 4;
    f32x4 bias = *(const f32x4*)(proj2_b + dcol0);
#pragma unroll
    for (int np = 0; np < 4; ++np) {
      f32x4 v = acc2[mtl][np] + bias;
      __builtin_nontemporal_store(v, (f32x4*)(out_gbf + (pairbase + np * 16 + lr) * 256 + dcol0));
    }
  }
}

extern "C" void kernel_launch(void* const* d_in, const int* in_sizes, int n_in,
                              void* d_out, int out_size, void* d_ws, size_t ws_size,
                              hipStream_t stream) {
  const float* positions = (const float*)d_in[0];
  const int* atomic_numbers = (const int*)d_in[1];
  const float* emb_z = (const float*)d_in[2];
  const float* electron_config = (const float*)d_in[3];
  const float* config_W = (const float*)d_in[4];
  const float* config_b = (const float*)d_in[5];
  const float* mult_W = (const float*)d_in[6];
  const float* charge_W = (const float*)d_in[7];
  const float* gbf_means = (const float*)d_in[8];
  const float* gbf_stds = (const float*)d_in[9];
  const float* gbf_mul = (const float*)d_in[10];
  const float* gbf_bias = (const float*)d_in[11];
  const float* proj1_W = (const float*)d_in[12];
  const float* proj1_b = (const float*)d_in[13];
  const float* proj2_W = (const float*)d_in[14];
  const float* proj2_b = (const float*)d_in[15];
  const float* dir_W = (const float*)d_in[16];
  const float* dir_b = (const float*)d_in[17];

  float* out = (float*)d_out;
  float* out_node = out;
  float* out_gbf = out + 262144;
  float* out_dir = out + 262144 + 67108864;

  char* ws = (char*)d_ws;
  __bf16* dirP = (__bf16*)(ws);
  __bf16* p1P = (__bf16*)(ws + 131072);
  __bf16* p2P = (__bf16*)(ws + 163840);
  float* f_az = (float*)(ws + 229376);
  float* f_po = (float*)(ws + 229376 + 256);
  f32x2* gAB = (f32x2*)(ws + 229376 + 512);
  float* gcoef = (float*)(ws + 229376 + 1536);

  setup_kernel<<<64, 256, 0, stream>>>(dir_W, proj1_W, proj2_W, gbf_stds, gbf_means,
                                       dirP, p1P, p2P, f_az, f_po, gAB, gcoef);
  pair_kernel<<<9216, 256, 0, stream>>>(positions, atomic_numbers, gbf_mul, gbf_bias,
                                        proj1_b, proj2_b, dir_b, dirP, p1P, p2P,
                                        f_az, f_po, gAB, gcoef,
                                        emb_z, electron_config, config_W, config_b,
                                        mult_W, charge_W,
                                        out_node, out_gbf, out_dir);
}